// Round 4
// baseline (209.665 us; speedup 1.0000x reference)
//
#include <hip/hip_runtime.h>

// Problem constants (static shapes from reference)
#define B 64
#define C 2048
#define H 24
#define W 8
#define HW (H * W)            // 192 spatial positions per (b,c)
#define HW4 (HW / 4)          // 48 float4s per spatial plane
#define CHUNKS 16             // channel chunks per batch
#define CPC (C / CHUNKS)      // 128 channels per chunk
#define RH 8                  // round(0.33 * 24) = 8 rows zeroed
#define NBLK (B * CHUNKS)     // 1024 blocks
#define ZSEG (B * C * RH)     // 1,048,576 zeroed 32-B row segments

// ---------------------------------------------------------------------------
// Kernel 1: streaming copy out=x + partial sum of squares per channel chunk.
// grid = B*CHUNKS blocks, block = 192 threads. 16 B/lane, 3072 B/block/iter
// contiguous for both the load and the store. Since HW(192) % 4 == 0, each
// thread's float4 has a fixed spatial phase across iterations, so a float4
// accumulator is exact; LDS-reduce the 4 channel sub-slices.
// ---------------------------------------------------------------------------
__global__ void __launch_bounds__(HW)
k_ss_copy(const float* __restrict__ x, float* __restrict__ out,
          float* __restrict__ partial) {
    __shared__ float4 sm4[HW];
    const int blk = blockIdx.x;
    const int b = blk / CHUNKS;
    const int chunk = blk % CHUNKS;
    const int t = threadIdx.x;  // 0..191

    const size_t region = (size_t)b * C * HW + (size_t)chunk * CPC * HW;
    const float4* p = (const float4*)(x + region) + t;
    float4* q = (float4*)(out + region) + t;

    float4 acc = {0.f, 0.f, 0.f, 0.f};
    #pragma unroll
    for (int j = 0; j < CPC / 4; ++j) {   // 32 iters, stride 4 channels
        const float4 v = p[(size_t)j * (4 * HW4)];
        q[(size_t)j * (4 * HW4)] = v;     // out = x (kept rows stay correct)
        acc.x += v.x * v.x;
        acc.y += v.y * v.y;
        acc.z += v.z * v.z;
        acc.w += v.w * v.w;
    }
    sm4[t] = acc;
    __syncthreads();
    if (t < HW4) {  // reduce the 4 channel sub-slices
        const float4 a0 = sm4[t];
        const float4 a1 = sm4[HW4 + t];
        const float4 a2 = sm4[2 * HW4 + t];
        const float4 a3 = sm4[3 * HW4 + t];
        float4 r;
        r.x = (a0.x + a1.x) + (a2.x + a3.x);
        r.y = (a0.y + a1.y) + (a2.y + a3.y);
        r.z = (a0.z + a1.z) + (a2.z + a3.z);
        r.w = (a0.w + a1.w) + (a2.w + a3.w);
        ((float4*)(partial + (size_t)blk * HW))[t] = r;
    }
}

// ---------------------------------------------------------------------------
// Kernel 2: reduce partials -> per-spatial sumsq -> per-row max over w ->
// rank rows, emit the RH selected row indices per batch.
// Tie-break (o == my && h > t) matches stable ascending argsort taking the
// LAST rh entries (larger index wins ties). Each selected row has a unique
// rank cnt in [0,RH) -> compact index write without atomics.
// ---------------------------------------------------------------------------
__global__ void k_mask(const float* __restrict__ partial, int* __restrict__ ind) {
    __shared__ float sm[HW];
    __shared__ float rs[H];
    const int b = blockIdx.x;
    const int t = threadIdx.x;

    float s = 0.f;
    #pragma unroll
    for (int ch = 0; ch < CHUNKS; ++ch)
        s += partial[((size_t)b * CHUNKS + ch) * HW + t];
    sm[t] = s;
    __syncthreads();

    if (t < H) {
        float m = sm[t * W];
        #pragma unroll
        for (int w = 1; w < W; ++w) m = fmaxf(m, sm[t * W + w]);
        rs[t] = m;
    }
    __syncthreads();

    if (t < H) {
        const float my = rs[t];
        int cnt = 0;
        #pragma unroll
        for (int h = 0; h < H; ++h) {
            const float o = rs[h];
            if (o > my || (o == my && h > t)) ++cnt;
        }
        if (cnt < RH) ind[b * RH + cnt] = t;  // selected: zero this row
    }
}

// ---------------------------------------------------------------------------
// Kernel 3: zero the selected rows. One thread per (b, c, r) 32-B segment:
// out[b, c, ind[b][r], 0..7] = 0. 33.5 MB of stores, no reads of x.
// grid = ZSEG/256 blocks, block = 256.
// ---------------------------------------------------------------------------
__global__ void k_zero(float* __restrict__ out, const int* __restrict__ ind) {
    const int g = blockIdx.x * 256 + threadIdx.x;  // < ZSEG
    const int b = g >> 14;          // / (C*RH)
    const int rem = g & 16383;
    const int c = rem >> 3;         // / RH
    const int r = rem & 7;          // % RH
    const int h = ind[b * RH + r];
    float4* dst = (float4*)(out + (size_t)b * C * HW + (size_t)c * HW + h * W);
    const float4 z = {0.f, 0.f, 0.f, 0.f};
    dst[0] = z;
    dst[1] = z;
}

// ---------------------------------------------------------------------------
extern "C" void kernel_launch(void* const* d_in, const int* in_sizes, int n_in,
                              void* d_out, int out_size, void* d_ws, size_t ws_size,
                              hipStream_t stream) {
    const float* x = (const float*)d_in[0];
    float* out = (float*)d_out;
    float* partial = (float*)d_ws;                    // NBLK*HW floats (768 KB)
    int* ind = (int*)(partial + (size_t)NBLK * HW);   // B*RH ints

    k_ss_copy<<<NBLK, HW, 0, stream>>>(x, out, partial);
    k_mask<<<B, HW, 0, stream>>>(partial, ind);
    k_zero<<<ZSEG / 256, 256, 0, stream>>>(out, ind);
}

// Round 6
// 189.880 us; speedup vs baseline: 1.1042x; 1.1042x over previous
//
#include <hip/hip_runtime.h>

// Problem constants (static shapes from reference)
#define B 64
#define C 2048
#define H 24
#define W 8
#define HW (H * W)            // 192 spatial positions per (b,c)
#define HW4 (HW / 4)          // 48 float4s per spatial plane
#define CHUNKS 16             // channel chunks per batch
#define CPC (C / CHUNKS)      // 128 channels per chunk
#define RH 8                  // round(0.33 * 24) = 8 rows zeroed
#define NBLK (B * CHUNKS)     // 1024 blocks

// native vector type for nontemporal builtins (HIP_vector_type is rejected)
typedef float floatx4 __attribute__((ext_vector_type(4)));

// ---------------------------------------------------------------------------
// Kernel 1: partial sum of squares per (batch, channel-chunk), float4 loads.
// grid = 1024 blocks x 192 threads; 16 B/lane, 3072 B/block/iter contiguous.
// HW(192) % 4 == 0 so each thread's float4 keeps a fixed spatial phase; the
// float4 accumulator is exact. LDS-reduce the 4 channel sub-slices ->
// partial[blk*HW + s]  (s = spatial index 0..191).
// ---------------------------------------------------------------------------
__global__ void __launch_bounds__(HW)
k_ss(const float* __restrict__ x, float* __restrict__ partial) {
    __shared__ floatx4 sm4[HW];
    const int blk = blockIdx.x;
    const int b = blk / CHUNKS;
    const int chunk = blk % CHUNKS;
    const int t = threadIdx.x;  // 0..191

    const size_t region = (size_t)b * C * HW + (size_t)chunk * CPC * HW;
    const floatx4* p = (const floatx4*)(x + region) + t;
    floatx4 acc = {0.f, 0.f, 0.f, 0.f};
    #pragma unroll
    for (int j = 0; j < CPC / 4; ++j) {   // 32 iters, stride 4 channels
        const floatx4 v = p[(size_t)j * (4 * HW4)];
        acc += v * v;
    }
    sm4[t] = acc;
    __syncthreads();
    if (t < HW4) {  // reduce the 4 channel sub-slices
        const floatx4 r = (sm4[t] + sm4[HW4 + t]) + (sm4[2 * HW4 + t] + sm4[3 * HW4 + t]);
        ((floatx4*)(partial + (size_t)blk * HW))[t] = r;
    }
}

// ---------------------------------------------------------------------------
// Kernel 2: fused mask + apply. grid = 1024 blocks x 192 threads, block
// (b,chunk) owns the same 96-KiB region as in k_ss.
//  a) redundantly reduce batch b's 16 partials (12 KB, L2-hit), per-row max
//     over w, rank rows (stable-argsort tiebreak: larger index wins ties),
//     0/1 mask for the 24 rows in LDS.
//  b) stream the region: L3-warm float4 load, multiply by the (per-thread
//     loop-invariant) mask, NONTEMPORAL float4 store — out is write-once,
//     keep it out of L2/L3 so x stays resident and no write pollution.
//     h = (t%48)>>1 since each h-row is exactly 2 float4s and 192%48==0.
// ---------------------------------------------------------------------------
__global__ void __launch_bounds__(HW)
k_apply_mask(const float* __restrict__ x, const float* __restrict__ partial,
             float* __restrict__ out) {
    __shared__ float sm[HW];
    __shared__ float rs[H];
    __shared__ float msk[H];
    const int blk = blockIdx.x;
    const int b = blk / CHUNKS;
    const int chunk = blk % CHUNKS;
    const int t = threadIdx.x;  // 0..191

    // ---- mask for batch b ----
    float s = 0.f;
    #pragma unroll
    for (int ch = 0; ch < CHUNKS; ++ch)
        s += partial[((size_t)b * CHUNKS + ch) * HW + t];
    sm[t] = s;
    __syncthreads();
    if (t < H) {
        float m = sm[t * W];
        #pragma unroll
        for (int w = 1; w < W; ++w) m = fmaxf(m, sm[t * W + w]);
        rs[t] = m;
    }
    __syncthreads();
    if (t < H) {
        const float my = rs[t];
        int cnt = 0;
        #pragma unroll
        for (int h = 0; h < H; ++h) {
            const float o = rs[h];
            if (o > my || (o == my && h > t)) ++cnt;
        }
        msk[t] = (cnt < RH) ? 0.0f : 1.0f;
    }
    __syncthreads();

    // ---- apply to own region ----
    const float m = msk[(t % 48) >> 1];  // loop-invariant per thread
    const size_t region = (size_t)b * C * HW + (size_t)chunk * CPC * HW;
    const floatx4* src = (const floatx4*)(x + region) + t;
    floatx4* dst = (floatx4*)(out + region) + t;
    #pragma unroll
    for (int j = 0; j < CPC / 4; ++j) {
        const floatx4 v = src[(size_t)j * (4 * HW4)];
        const floatx4 r = v * m;
        __builtin_nontemporal_store(r, &dst[(size_t)j * (4 * HW4)]);
    }
}

// ---------------------------------------------------------------------------
extern "C" void kernel_launch(void* const* d_in, const int* in_sizes, int n_in,
                              void* d_out, int out_size, void* d_ws, size_t ws_size,
                              hipStream_t stream) {
    const float* x = (const float*)d_in[0];
    float* out = (float*)d_out;
    float* partial = (float*)d_ws;  // NBLK*HW floats (768 KB)

    k_ss<<<NBLK, HW, 0, stream>>>(x, partial);
    k_apply_mask<<<NBLK, HW, 0, stream>>>(x, partial, out);
}